// Round 11
// baseline (200.832 us; speedup 1.0000x reference)
//
#include <hip/hip_runtime.h>

#define D 128
#define TILE 16
#define CAP 64            // max degree slot capacity; Poisson(16) tail @64 ~1e-19

typedef short bf16x8 __attribute__((ext_vector_type(8)));
typedef float f32x4  __attribute__((ext_vector_type(4)));
typedef float f32x2  __attribute__((ext_vector_type(2)));

static __device__ __forceinline__ unsigned f2bf(float x) {
    unsigned u = __float_as_uint(x);
    return (u + 0x7FFFu + ((u >> 16) & 1u)) >> 16;   // RNE
}
static __device__ __forceinline__ float blo(unsigned v) { return __uint_as_float(v << 16); }
static __device__ __forceinline__ float bhi(unsigned v) { return __uint_as_float(v & 0xFFFF0000u); }

// ---- f32->bf16 convert (h, W) + zero-fill (cnt) in one dispatch ----
__global__ __launch_bounds__(256) void cvt2z_kernel(const float4* __restrict__ a,
                                                    uint2* __restrict__ oa, int n4a,
                                                    const float4* __restrict__ bsrc,
                                                    uint2* __restrict__ ob, int n4b,
                                                    int4* __restrict__ zbuf, int nz4) {
    int i = blockIdx.x * 256 + threadIdx.x;
    if (i < n4a) {
        float4 v = a[i];
        uint2 o;
        o.x = f2bf(v.x) | (f2bf(v.y) << 16);
        o.y = f2bf(v.z) | (f2bf(v.w) << 16);
        oa[i] = o;
    }
    int j = i - n4a;
    if (j >= 0 && j < n4b) {
        float4 v = bsrc[j];
        uint2 o;
        o.x = f2bf(v.x) | (f2bf(v.y) << 16);
        o.y = f2bf(v.z) | (f2bf(v.w) << 16);
        ob[j] = o;
    }
    int k = j - n4b;
    if (k >= 0 && k < nz4) zbuf[k] = make_int4(0, 0, 0, 0);
}

// ---- single-pass CSR build: direct slot = (dst<<6) + arrival rank ----
__global__ __launch_bounds__(256) void build_kernel(const int* __restrict__ src,
                                                    const int* __restrict__ dst,
                                                    const float* __restrict__ wself,
                                                    const float* __restrict__ wppi,
                                                    int* __restrict__ cnt,
                                                    uint2* __restrict__ edges, int E) {
    int i = blockIdx.x * 256 + threadIdx.x;
    if (i < E) {
        int d = dst[i];
        int r = atomicAdd(&cnt[d], 1);
        if (r < CAP) {
            uint2 e;
            e.x = (unsigned)src[i];
            e.y = f2bf(wself[i]) | (f2bf(wppi[i]) << 16);
            edges[(d << 6) + r] = e;
        }
    }
}

// ---------------- fused layer: dual agg (LDS) + MFMA update ----------------
// Block = 512 threads = 8 waves; tile = 16 nodes. Wave w aggregates nodes
// w and w+8 in LOCKSTEP: per iteration, 4+4 masked edge-record loads then
// 8 h-row loads (16 B/lane, quarter-wave split: 16 lanes cover one 256 B row,
// 4 edges per load instr) in flight, then packed-f32 FMAs into separate
// accumulator banks. Inactive lanes get a zero record (weights = 0) via
// exec-masked select -> no scale array, no deg-0 hazard.
// Phase 2: all 8 waves, one o-tile each via bf16 MFMA.
__global__ __launch_bounds__(512, 4) void layer_kernel(const unsigned short* __restrict__ h16,
                                                       const int* __restrict__ cnt,
                                                       const uint2* __restrict__ edges,
                                                       const unsigned short* __restrict__ Wb,
                                                       const float* __restrict__ bias,
                                                       float* __restrict__ out,
                                                       unsigned short* __restrict__ out16,
                                                       int n) {
    __shared__ unsigned short ppi_lds[TILE][136];   // 272 B row stride: 16 B aligned
    __shared__ float          res_lds[TILE][132];   // 528 B row stride: 16 B aligned
    int t = threadIdx.x;
    int w = t >> 6, lane = t & 63;
    int tile = blockIdx.x;
    int q  = lane >> 4;        // quarter: which edge of 4 this lane serves
    int c8 = lane & 15;        // channel group: channels 8*c8 .. 8*c8+7

    int nodeA = tile * TILE + w;       // n divisible by 16
    int nodeB = nodeA + 8;
    int degA = min(cnt[nodeA], CAP);
    int degB = min(cnt[nodeB], CAP);
    int begA = nodeA << 6, begB = nodeB << 6;

    f32x2 rA[4] = {{0.f,0.f},{0.f,0.f},{0.f,0.f},{0.f,0.f}};
    f32x2 pA[4] = {{0.f,0.f},{0.f,0.f},{0.f,0.f},{0.f,0.f}};
    f32x2 rB[4] = {{0.f,0.f},{0.f,0.f},{0.f,0.f},{0.f,0.f}};
    f32x2 pB[4] = {{0.f,0.f},{0.f,0.f},{0.f,0.f},{0.f,0.f}};

    int nb = max((degA + 15) >> 4, (degB + 15) >> 4);
    const uint2 zed = make_uint2(0u, 0u);
    for (int b = 0; b < nb; ++b) {
        uint2 erA[4], erB[4];
        #pragma unroll
        for (int j = 0; j < 4; ++j) {
            int ia = b * 16 + 4 * j + q;
            erA[j] = (ia < degA) ? edges[begA + ia] : zed;
            erB[j] = (ia < degB) ? edges[begB + ia] : zed;
        }
        uint4 hvA[4], hvB[4];
        #pragma unroll
        for (int j = 0; j < 4; ++j) {
            hvA[j] = *(const uint4*)(h16 + (size_t)erA[j].x * D + c8 * 8);
            hvB[j] = *(const uint4*)(h16 + (size_t)erB[j].x * D + c8 * 8);
        }
        #pragma unroll
        for (int j = 0; j < 4; ++j) {
            float a = blo(erA[j].y), bwt = bhi(erA[j].y);
            f32x2 av = {a, a}, bv = {bwt, bwt};
            f32x2 h01 = {blo(hvA[j].x), bhi(hvA[j].x)};
            f32x2 h23 = {blo(hvA[j].y), bhi(hvA[j].y)};
            f32x2 h45 = {blo(hvA[j].z), bhi(hvA[j].z)};
            f32x2 h67 = {blo(hvA[j].w), bhi(hvA[j].w)};
            rA[0] = __builtin_elementwise_fma(av, h01, rA[0]);
            rA[1] = __builtin_elementwise_fma(av, h23, rA[1]);
            rA[2] = __builtin_elementwise_fma(av, h45, rA[2]);
            rA[3] = __builtin_elementwise_fma(av, h67, rA[3]);
            pA[0] = __builtin_elementwise_fma(bv, h01, pA[0]);
            pA[1] = __builtin_elementwise_fma(bv, h23, pA[1]);
            pA[2] = __builtin_elementwise_fma(bv, h45, pA[2]);
            pA[3] = __builtin_elementwise_fma(bv, h67, pA[3]);

            float a2 = blo(erB[j].y), bwt2 = bhi(erB[j].y);
            f32x2 av2 = {a2, a2}, bv2 = {bwt2, bwt2};
            f32x2 g01 = {blo(hvB[j].x), bhi(hvB[j].x)};
            f32x2 g23 = {blo(hvB[j].y), bhi(hvB[j].y)};
            f32x2 g45 = {blo(hvB[j].z), bhi(hvB[j].z)};
            f32x2 g67 = {blo(hvB[j].w), bhi(hvB[j].w)};
            rB[0] = __builtin_elementwise_fma(av2, g01, rB[0]);
            rB[1] = __builtin_elementwise_fma(av2, g23, rB[1]);
            rB[2] = __builtin_elementwise_fma(av2, g45, rB[2]);
            rB[3] = __builtin_elementwise_fma(av2, g67, rB[3]);
            pB[0] = __builtin_elementwise_fma(bv2, g01, pB[0]);
            pB[1] = __builtin_elementwise_fma(bv2, g23, pB[1]);
            pB[2] = __builtin_elementwise_fma(bv2, g45, pB[2]);
            pB[3] = __builtin_elementwise_fma(bv2, g67, pB[3]);
        }
    }

    // ---- cross-quarter reduction + LDS store for both nodes ----
    {
        float r[8] = {rA[0].x, rA[0].y, rA[1].x, rA[1].y, rA[2].x, rA[2].y, rA[3].x, rA[3].y};
        float p[8] = {pA[0].x, pA[0].y, pA[1].x, pA[1].y, pA[2].x, pA[2].y, pA[3].x, pA[3].y};
        float s[8] = {rB[0].x, rB[0].y, rB[1].x, rB[1].y, rB[2].x, rB[2].y, rB[3].x, rB[3].y};
        float u[8] = {pB[0].x, pB[0].y, pB[1].x, pB[1].y, pB[2].x, pB[2].y, pB[3].x, pB[3].y};
        #pragma unroll
        for (int i = 0; i < 8; ++i) {
            r[i] += __shfl_xor(r[i], 16, 64); r[i] += __shfl_xor(r[i], 32, 64);
            p[i] += __shfl_xor(p[i], 16, 64); p[i] += __shfl_xor(p[i], 32, 64);
            s[i] += __shfl_xor(s[i], 16, 64); s[i] += __shfl_xor(s[i], 32, 64);
            u[i] += __shfl_xor(u[i], 16, 64); u[i] += __shfl_xor(u[i], 32, 64);
        }
        if (q == 0) {
            *(float4*)&res_lds[w][c8 * 8]     = make_float4(r[0], r[1], r[2], r[3]);
            *(float4*)&res_lds[w][c8 * 8 + 4] = make_float4(r[4], r[5], r[6], r[7]);
            uint4 o;
            o.x = f2bf(p[0]) | (f2bf(p[1]) << 16);
            o.y = f2bf(p[2]) | (f2bf(p[3]) << 16);
            o.z = f2bf(p[4]) | (f2bf(p[5]) << 16);
            o.w = f2bf(p[6]) | (f2bf(p[7]) << 16);
            *(uint4*)&ppi_lds[w][c8 * 8] = o;

            *(float4*)&res_lds[w + 8][c8 * 8]     = make_float4(s[0], s[1], s[2], s[3]);
            *(float4*)&res_lds[w + 8][c8 * 8 + 4] = make_float4(s[4], s[5], s[6], s[7]);
            uint4 o2;
            o2.x = f2bf(u[0]) | (f2bf(u[1]) << 16);
            o2.y = f2bf(u[2]) | (f2bf(u[3]) << 16);
            o2.z = f2bf(u[4]) | (f2bf(u[5]) << 16);
            o2.w = f2bf(u[6]) | (f2bf(u[7]) << 16);
            *(uint4*)&ppi_lds[w + 8][c8 * 8] = o2;
        }
    }
    __syncthreads();

    // ---- phase 2: MFMA update, wave w handles o-tile w ----
    {
        int m16 = lane & 15, quad = lane >> 4;
        bf16x8 a[4];
        const unsigned short* arow = &ppi_lds[m16][quad * 8];
        #pragma unroll
        for (int kt = 0; kt < 4; ++kt) a[kt] = *(const bf16x8*)(arow + kt * 32);

        const unsigned short* brow = Wb + (size_t)(w * 16 + m16) * D + quad * 8;
        bf16x8 bfr[4];
        #pragma unroll
        for (int kt = 0; kt < 4; ++kt) bfr[kt] = *(const bf16x8*)(brow + kt * 32);

        f32x4 acc = {0.f, 0.f, 0.f, 0.f};
        #pragma unroll
        for (int kt = 0; kt < 4; ++kt)
            acc = __builtin_amdgcn_mfma_f32_16x16x32_bf16(a[kt], bfr[kt], acc, 0, 0, 0);

        int o = w * 16 + m16;
        float bb = bias[o];
        #pragma unroll
        for (int r = 0; r < 4; ++r) {
            int nd = quad * 4 + r;
            float v = fmaxf(acc[r] + bb, 0.f) + res_lds[nd][o];
            size_t gi = (size_t)(tile * TILE + nd) * D + o;
            if (out)   out[gi] = v;
            if (out16) out16[gi] = (unsigned short)f2bf(v);
        }
    }
}

// ---------------- launch ----------------
extern "C" void kernel_launch(void* const* d_in, const int* in_sizes, int n_in,
                              void* d_out, int out_size, void* d_ws, size_t ws_size,
                              hipStream_t stream) {
    const float* h0    = (const float*)d_in[0];
    const int*   esrc  = (const int*)d_in[1];
    const int*   edst  = (const int*)d_in[2];
    const float* wself = (const float*)d_in[3];
    const float* wppi  = (const float*)d_in[4];
    const float* W     = (const float*)d_in[5];
    const float* b     = (const float*)d_in[6];
    float*       out   = (float*)d_out;

    const int N = in_sizes[0] / D;
    const int E = in_sizes[1];
    const int L = in_sizes[5] / (D * D);

    char* ws = (char*)d_ws;
    unsigned short* h16a  = (unsigned short*)ws; ws += (size_t)N * D * 2;    // 10.24 MB
    unsigned short* h16b  = (unsigned short*)ws; ws += (size_t)N * D * 2;    // 10.24 MB
    uint2*          edges = (uint2*)ws;          ws += (size_t)N * CAP * 8;  // 20.48 MB
    unsigned short* Wb    = (unsigned short*)ws; ws += (size_t)L * D * D * 2;
    int* cnt = (int*)ws;  ws += (size_t)N * 4;

    int n4h = N * D / 4;
    int n4w = L * D * D / 4;
    int nz4 = N / 4;                                     // N divisible by 4
    int tot = n4h + n4w + nz4;
    cvt2z_kernel<<<(tot + 255) / 256, 256, 0, stream>>>(
        (const float4*)h0, (uint2*)h16a, n4h,
        (const float4*)W, (uint2*)Wb, n4w,
        (int4*)cnt, nz4);

    int eb = (E + 255) / 256;
    build_kernel<<<eb, 256, 0, stream>>>(esrc, edst, wself, wppi, cnt, edges, E);

    int ntiles = N / TILE;   // 2500
    layer_kernel<<<ntiles, 512, 0, stream>>>(h16a, cnt, edges, Wb, b,
                                             (L > 1) ? nullptr : out,
                                             (L > 1) ? h16b : nullptr, N);
    for (int l = 1; l < L; ++l) {
        bool last = (l + 1 == L);
        layer_kernel<<<ntiles, 512, 0, stream>>>(h16b, cnt, edges,
                                                 Wb + (size_t)l * D * D, b + (size_t)l * D,
                                                 last ? out : nullptr,
                                                 last ? nullptr : h16a, N);
        unsigned short* tmp = h16a; h16a = h16b; h16b = tmp;
    }
}